// Round 10
// baseline (1424.574 us; speedup 1.0000x reference)
//
#include <hip/hip_runtime.h>
#include <math.h>

#define D_    256
#define H_    256
#define R_    8
#define NINIT 8192
#define LL    16
#define MM    4096
#define NTOT  (NINIT + LL*MM)   // 73728
#define NTILE 256               // tiles per layer = 4096/16, tight-packed (no padding)
#define NBLK  256               // persistent grid: one block per tile slot, 1/CU
#define KS1   16                // K-steps GEMM1 (512/32)
#define KS2   8                 // K-steps GEMM2 (256/32)
#define NT    16                // n-tiles (256/16)

#define EMB_BLKS (NINIT*64/256)        // 2048
#define PK1_BLKS (R_*KS1*NT*64/256)    // 512
#define PK2_BLKS (R_*KS2*NT*64/256)    // 256
#define PREP_BLKS (LL + EMB_BLKS + PK1_BLKS + PK2_BLKS)
#define NPART (LL*NTILE + EMB_BLKS)    // 6144 partial slots (6 floats each)

typedef __attribute__((ext_vector_type(8))) short short8;
typedef __attribute__((ext_vector_type(4))) float f32x4;

__device__ __forceinline__ uint bf16h(float f) {           // f32 -> bf16 bits (RNE)
    uint u = __float_as_uint(f);
    return (u + 0x7fffu + ((u >> 16) & 1u)) >> 16;
}
__device__ __forceinline__ float bf16f(uint h) { return __uint_as_float(h << 16); }

__device__ __forceinline__ void bce_terms(float val, float lab, float p, float ng,
                                          float* A, float* B, float* pOK, float* nOK,
                                          float* tp, float* tn) {
    float tot = p + ng;
    float target = p / fmaxf(tot, 1e-8f);
    float ls  = (val >= 0.f) ? -log1pf(expf(-val)) : (val  - log1pf(expf( val)));
    float lns = (val <= 0.f) ? -log1pf(expf( val)) : (-val - log1pf(expf(-val)));
    *A = lab*tot*target*ls;
    *B = lab*tot*(1.f - target)*lns;
    *pOK = (val >= 0.f) ? lab*p : 0.f;
    *nOK = (val <  0.f) ? lab*ng : 0.f;
    *tp = p*lab; *tn = ng*lab;
}

// ---------------- prep bodies ----------------
// tight counting sort (no padding) + exact prefix sums; also resets the grid barrier
__device__ void sort_body(int l, int t, const int* __restrict__ rule,
                          int* __restrict__ sorted, int* __restrict__ prefix,
                          int* __restrict__ bar) {
    __shared__ int hist[R_], cursor[R_], pre[R_+1];
    if (l == 0 && t == 0) *bar = 0;
    if (t < R_) hist[t] = 0;
    __syncthreads();
    for (int m = t; m < MM; m += 256) atomicAdd(&hist[rule[l*MM + m]], 1);
    __syncthreads();
    if (t == 0) {
        pre[0] = 0;
        for (int r = 0; r < R_; r++) { pre[r+1] = pre[r] + hist[r]; cursor[r] = pre[r]; }
    }
    __syncthreads();
    if (t < R_+1) prefix[l*(R_+1) + t] = pre[t];
    for (int m = t; m < MM; m += 256) {
        int r = rule[l*MM + m];
        int p = atomicAdd(&cursor[r], 1);
        sorted[l*MM + p] = m;
    }
}

// embed + fused eval for init nodes (one wave = one node; block = 4 nodes)
__device__ void embed_body(int b, int t, const float* __restrict__ itab,
                           const float* __restrict__ stab,
                           const int* __restrict__ thax, const int* __restrict__ sine,
                           float* __restrict__ store,
                           const float* __restrict__ w_eval, const float* __restrict__ b_eval,
                           const float* __restrict__ t_eval, const float* __restrict__ pt,
                           const float* __restrict__ pos, const float* __restrict__ neg,
                           const int* __restrict__ labeled, float* __restrict__ partials) {
    __shared__ float ered[4][6];
    int gid = b*256 + t;
    int n = gid >> 6, d = (gid & 63) << 2;
    int th = thax[n], si = sine[n];
    const float4 a = *(const float4*)&itab[th*D_ + d];
    const float4 bb = *(const float4*)&stab[si*D_ + d];
    float4 o; o.x = a.x+bb.x; o.y = a.y+bb.y; o.z = a.z+bb.z; o.w = a.w+bb.w;
    *(float4*)&store[(size_t)n*D_ + d] = o;
    const float4 we = *(const float4*)&w_eval[d];
    float pv = o.x*we.x + o.y*we.y + o.z*we.z + o.w*we.w;
    #pragma unroll
    for (int off = 32; off > 0; off >>= 1) pv += __shfl_xor(pv, off);
    int wvid = t >> 6;
    if ((t & 63) == 0) {
        float val = pv + b_eval[0] + pt[0]*t_eval[0];
        float A, B, pOK, nOK, tp, tn;
        bce_terms(val, (float)labeled[n], pos[n], neg[n], &A, &B, &pOK, &nOK, &tp, &tn);
        ered[wvid][0]=A; ered[wvid][1]=B; ered[wvid][2]=pOK;
        ered[wvid][3]=nOK; ered[wvid][4]=tp; ered[wvid][5]=tn;
    }
    __syncthreads();
    if (t < 6) partials[((size_t)LL*NTILE + b)*6 + t] =
        ered[0][t] + ered[1][t] + ered[2][t] + ered[3][t];
}

// Ph[((r*KSn + ks)*NT + nt)*64 + lane][j] = bf16(W[r][ks*32 + (lane>>4)*8 + j][nt*16 + (lane&15)])
__device__ void pack_body(int gid, const float* __restrict__ W,
                          ushort* __restrict__ Ph, int KSn) {
    int lane = gid & 63;
    int nt   = (gid >> 6) & 15;
    int ks   = (gid >> 10) % KSn;
    int r    = gid / (1024*KSn);
    int K = KSn*32;
    int k0 = ks*32 + (lane >> 4)*8;
    int c  = nt*16 + (lane & 15);
    const float* src = W + ((size_t)r*K + k0)*256 + c;
    uint h[8];
    #pragma unroll
    for (int j = 0; j < 8; j++) h[j] = bf16h(src[(size_t)j*256]);
    size_t o = (size_t)gid*8;
    *(uint4*)&Ph[o] = make_uint4(h[0]|(h[1]<<16), h[2]|(h[3]<<16), h[4]|(h[5]<<16), h[6]|(h[7]<<16));
}

__global__ __launch_bounds__(256) void prep_kernel(
        const int* __restrict__ drule, int* __restrict__ sorted, int* __restrict__ prefix,
        int* __restrict__ bar,
        const float* __restrict__ itab, const float* __restrict__ stab,
        const int* __restrict__ thax, const int* __restrict__ sine,
        float* __restrict__ store,
        const float* __restrict__ W1, ushort* __restrict__ P1h,
        const float* __restrict__ W2, ushort* __restrict__ P2h,
        const float* __restrict__ w_eval, const float* __restrict__ b_eval,
        const float* __restrict__ t_eval, const float* __restrict__ pt,
        const float* __restrict__ pos, const float* __restrict__ neg,
        const int* __restrict__ labeled, float* __restrict__ partials) {
    int b = blockIdx.x, t = threadIdx.x;
    if (b < LL) {
        sort_body(b, t, drule, sorted, prefix, bar);
    } else if (b < LL + EMB_BLKS) {
        embed_body(b - LL, t, itab, stab, thax, sine, store,
                   w_eval, b_eval, t_eval, pt, pos, neg, labeled, partials);
    } else if (b < LL + EMB_BLKS + PK1_BLKS) {
        pack_body((b - LL - EMB_BLKS)*256 + t, W1, P1h, KS1);
    } else {
        pack_body((b - LL - EMB_BLKS - PK1_BLKS)*256 + t, W2, P2h, KS2);
    }
}

// ---------------- persistent kernel: all 16 layers + final reduce ----------------
struct PParams {
    float* store; const int* sorted; const int* prefix; const int* parents;
    const ushort* P1h; const ushort* P2h;
    const float* b1; const float* t1; const float* b2; const float* pt;
    const float* w_eval; const float* b_eval; const float* t_eval;
    const float* pos; const float* neg; const int* labeled;
    float* partials; float* out; int* bar;
};

__global__ __launch_bounds__(1024) void persist_kernel(PParams P) {
    __shared__ ushort Xh[16*512], Xl[16*512];   // 16 rows x 512 bf16 hi/lo, swizzled
    __shared__ ushort Hh[16*256], Hl[16*256];
    __shared__ int idx_s[16];
    __shared__ int pre_s[R_+1];
    __shared__ float vred[16][17];
    __shared__ float red2[1024];

    const int t = threadIdx.x, lane = t & 63, wv = t >> 6;   // wv = 0..15
    const int crow = lane & 15, kg = lane >> 4;
    const int tl = blockIdx.x;                                // tile 0..255
    const float tw = P.pt[1];
    const float bev = P.b_eval[0] + P.pt[0]*P.t_eval[0];
    const int col = wv*16 + crow;
    const float we = P.w_eval[col];

    for (int l = 0; l < LL; l++) {
        if (t < R_+1) pre_s[t] = P.prefix[l*(R_+1) + t];
        // ---- gather: wave wv stages row wv (2 parent halves, float4/lane) ----
        const int m = P.sorted[l*MM + tl*16 + wv];
        if (lane == 0) idx_s[wv] = m;
        #pragma unroll
        for (int half = 0; half < 2; half++) {
            int pn = P.parents[(l*MM + m)*2 + half];
            float4 v = *(const float4*)&P.store[(size_t)pn*D_ + lane*4];
            uint h0 = bf16h(v.x), h1 = bf16h(v.y), h2 = bf16h(v.z), h3 = bf16h(v.w);
            uint l0 = bf16h(v.x - bf16f(h0)), l1 = bf16h(v.y - bf16f(h1));
            uint l2 = bf16h(v.z - bf16f(h2)), l3 = bf16h(v.w - bf16f(h3));
            int e = half*256 + lane*4;
            int boff = (e*2) ^ ((wv & 7) << 4);
            *(uint2*)&Xh[wv*512 + (boff >> 1)] = make_uint2(h0|(h1<<16), h2|(h3<<16));
            *(uint2*)&Xl[wv*512 + (boff >> 1)] = make_uint2(l0|(l1<<16), l2|(l3<<16));
        }
        __syncthreads();

        const int row0 = tl*16;
        const int ob = NINIT + l*MM;
        // ---- rule passes: uniform tiles run once; straddle tiles once per rule ----
        for (int r = 0; r < R_; r++) {
            int lo = (row0 > pre_s[r] ? row0 : pre_s[r]) - row0;
            int hi = (row0+16 < pre_s[r+1] ? row0+16 : pre_s[r+1]) - row0;
            if (lo >= hi) continue;
            float bb1 = P.b1[r*H_ + col] + tw * P.t1[r*H_ + col];
            float bb2 = P.b2[r*D_ + col];

            // GEMM1: [16x512] @ W1h[512x256], 2-pass (xl, xh)
            f32x4 acc = (f32x4){bb1, bb1, bb1, bb1};
            const short8* B1hp = (const short8*)P.P1h + ((size_t)r*KS1*NT + wv)*64 + lane;
            #pragma unroll
            for (int ks = 0; ks < KS1; ks++) {
                int ab = ((ks*64 + kg*16) ^ ((crow & 7) << 4)) >> 1;
                short8 xh = *(const short8*)&Xh[crow*512 + ab];
                short8 xl = *(const short8*)&Xl[crow*512 + ab];
                short8 bh = B1hp[(size_t)ks*NT*64];
                acc = __builtin_amdgcn_mfma_f32_16x16x32_bf16(xl, bh, acc, 0, 0, 0);
                acc = __builtin_amdgcn_mfma_f32_16x16x32_bf16(xh, bh, acc, 0, 0, 0);
            }
            __syncthreads();                      // previous pass done reading H
            #pragma unroll
            for (int reg = 0; reg < 4; reg++) {
                int row = kg*4 + reg;
                float h = fmaxf(acc[reg], 0.f);
                uint hh = bf16h(h);
                uint hl = bf16h(h - bf16f(hh));
                int boff = (col*2) ^ ((row & 7) << 4);
                Hh[row*256 + (boff >> 1)] = (ushort)hh;
                Hl[row*256 + (boff >> 1)] = (ushort)hl;
            }
            __syncthreads();

            // GEMM2: [16x256] @ W2h[256x256], 2-pass (hl, hh)
            f32x4 acc2 = (f32x4){bb2, bb2, bb2, bb2};
            const short8* B2hp = (const short8*)P.P2h + ((size_t)r*KS2*NT + wv)*64 + lane;
            #pragma unroll
            for (int ks = 0; ks < KS2; ks++) {
                int ab = ((ks*64 + kg*16) ^ ((crow & 7) << 4)) >> 1;
                short8 hh = *(const short8*)&Hh[crow*256 + ab];
                short8 hl = *(const short8*)&Hl[crow*256 + ab];
                short8 bh = B2hp[(size_t)ks*NT*64];
                acc2 = __builtin_amdgcn_mfma_f32_16x16x32_bf16(hl, bh, acc2, 0, 0, 0);
                acc2 = __builtin_amdgcn_mfma_f32_16x16x32_bf16(hh, bh, acc2, 0, 0, 0);
            }
            // store y + eval partial-dot for rows owned by rule r
            float pv[4];
            #pragma unroll
            for (int reg = 0; reg < 4; reg++) {
                int row = kg*4 + reg;
                if (row >= lo && row < hi)
                    P.store[(size_t)(ob + idx_s[row])*D_ + col] = acc2[reg];
                pv[reg] = acc2[reg] * we;
            }
            #pragma unroll
            for (int off = 1; off < 16; off <<= 1) {
                #pragma unroll
                for (int reg = 0; reg < 4; reg++) pv[reg] += __shfl_xor(pv[reg], off);
            }
            if (crow == 0) {
                #pragma unroll
                for (int reg = 0; reg < 4; reg++) {
                    int row = kg*4 + reg;
                    if (row >= lo && row < hi) vred[row][wv] = pv[reg];
                }
            }
        }
        __syncthreads();
        // ---- fused eval tail: one row per lane (t < 16) ----
        if (t < 16) {
            float val = 0.f;
            #pragma unroll
            for (int w16 = 0; w16 < 16; w16++) val += vred[t][w16];
            int n = ob + idx_s[t];
            float A, B, pOK, nOK, tp, tn;
            bce_terms(val + bev, (float)P.labeled[n], P.pos[n], P.neg[n],
                      &A, &B, &pOK, &nOK, &tp, &tn);
            #pragma unroll
            for (int off = 1; off < 16; off <<= 1) {
                A   += __shfl_xor(A, off);   B  += __shfl_xor(B, off);
                pOK += __shfl_xor(pOK, off); nOK += __shfl_xor(nOK, off);
                tp  += __shfl_xor(tp, off);  tn += __shfl_xor(tn, off);
            }
            if (t == 0) {
                float* ps = &P.partials[((size_t)l*NTILE + tl)*6];
                ps[0]=A; ps[1]=B; ps[2]=pOK; ps[3]=nOK; ps[4]=tp; ps[5]=tn;
            }
        }
        // ---- grid barrier (monotonic counter; device-scope fences for cross-XCD) ----
        __syncthreads();                           // drains vmcnt: all stores in L2
        if (t == 0) {
            __threadfence();                       // release: writeback L2
            atomicAdd(P.bar, 1);
            int target = NBLK*(l+1);
            while (atomicAdd(P.bar, 0) < target) __builtin_amdgcn_s_sleep(2);
        }
        __syncthreads();
        __threadfence();                           // acquire: invalidate stale L1/L2
    }

    // ---- final reduce + pw + loss (block 0) ----
    if (tl == 0) {
        float s[6] = {0.f, 0.f, 0.f, 0.f, 0.f, 0.f};
        for (int g = t; g < NPART; g += 1024) {
            #pragma unroll
            for (int j = 0; j < 6; j++) s[j] += P.partials[g*6 + j];
        }
        for (int j = 0; j < 6; j++) {
            __syncthreads();
            red2[t] = s[j];
            __syncthreads();
            for (int st = 512; st > 0; st >>= 1) {
                if (t < st) red2[t] += red2[t + st];
                __syncthreads();
            }
            s[j] = red2[0];
        }
        if (t == 0) {
            float pw = s[5] / fmaxf(s[4], 1e-8f);
            P.out[0] = -(pw*s[0] + s[1]);
            P.out[1] = s[2]; P.out[2] = s[3]; P.out[3] = s[4]; P.out[4] = s[5];
        }
    }
}

extern "C" void kernel_launch(void* const* d_in, const int* in_sizes, int n_in,
                              void* d_out, int out_size, void* d_ws, size_t ws_size,
                              hipStream_t stream) {
    const float* pt        = (const float*)d_in[0];
    const float* init_tab  = (const float*)d_in[1];
    const float* sine_tab  = (const float*)d_in[2];
    const float* W1        = (const float*)d_in[3];
    const float* b1        = (const float*)d_in[4];
    const float* t1        = (const float*)d_in[5];
    const float* W2        = (const float*)d_in[6];
    const float* b2        = (const float*)d_in[7];
    const float* w_eval    = (const float*)d_in[8];
    const float* b_eval    = (const float*)d_in[9];
    const float* t_eval    = (const float*)d_in[10];
    const float* pos       = (const float*)d_in[11];
    const float* neg       = (const float*)d_in[12];
    const int*   init_thax = (const int*)d_in[13];
    const int*   init_sine = (const int*)d_in[14];
    const int*   drule     = (const int*)d_in[15];
    const int*   dparents  = (const int*)d_in[16];
    const int*   labeled   = (const int*)d_in[17];
    float* out = (float*)d_out;

    // workspace layout (bytes, all 16-aligned)
    char* w = (char*)d_ws;
    const size_t STORE_B = (size_t)NTOT * D_ * 4;            // 75,497,472
    const size_t SORT_B  = (size_t)LL * MM * 4;              //    262,144
    const size_t PREF_B  = 1024;                             // LL*9*4 padded
    const size_t P1_B    = (size_t)R_*KS1*NT*64*8*2;         //  2,097,152
    const size_t P2_B    = (size_t)R_*KS2*NT*64*8*2;         //  1,048,576
    const size_t PART_B  = (size_t)NPART*6*4;                //    147,456
    float*  store    = (float*) w;                    w += STORE_B;
    int*    sorted   = (int*)   w;                    w += SORT_B;
    int*    prefix   = (int*)   w;                    w += PREF_B;
    ushort* P1h      = (ushort*)w;                    w += P1_B;
    ushort* P2h      = (ushort*)w;                    w += P2_B;
    float*  partials = (float*) w;                    w += PART_B;
    int*    bar      = (int*)   w;

    prep_kernel<<<PREP_BLKS, 256, 0, stream>>>(drule, sorted, prefix, bar,
                                               init_tab, sine_tab,
                                               init_thax, init_sine, store,
                                               W1, P1h, W2, P2h,
                                               w_eval, b_eval, t_eval, pt,
                                               pos, neg, labeled, partials);
    PParams P;
    P.store = store; P.sorted = sorted; P.prefix = prefix; P.parents = dparents;
    P.P1h = P1h; P.P2h = P2h;
    P.b1 = b1; P.t1 = t1; P.b2 = b2; P.pt = pt;
    P.w_eval = w_eval; P.b_eval = b_eval; P.t_eval = t_eval;
    P.pos = pos; P.neg = neg; P.labeled = labeled;
    P.partials = partials; P.out = out; P.bar = bar;
    persist_kernel<<<NBLK, 1024, 0, stream>>>(P);
}

// Round 11
// 276.157 us; speedup vs baseline: 5.1586x; 5.1586x over previous
//
#include <hip/hip_runtime.h>
#include <math.h>

#define D_    256
#define H_    256
#define R_    8
#define NINIT 8192
#define LL    16
#define MM    4096
#define NTOT  (NINIT + LL*MM)   // 73728
#define NTILE 256               // tiles per layer = 4096/16, tight-packed
#define KS1   16                // K-steps GEMM1 (512/32)
#define KS2   8                 // K-steps GEMM2 (256/32)
#define NT    16                // n-tiles (256/16)
#define XROW  520               // X row pitch in ushorts (1040B: 16B-aligned, bank-rot 4)
#define HROW  264               // H row pitch in ushorts (528B: 16B-aligned, bank-rot 4)

#define EMB_BLKS (NINIT*64/256)        // 2048
#define PK1_BLKS (R_*KS1*NT*64/256)    // 512
#define PK2_BLKS (R_*KS2*NT*64/256)    // 256
#define PREP_BLKS (LL + EMB_BLKS + PK1_BLKS + PK2_BLKS)
#define NPART (LL*NTILE + EMB_BLKS)    // 6144 partial slots (6 floats each)

typedef __attribute__((ext_vector_type(8))) short short8;
typedef __attribute__((ext_vector_type(4))) float f32x4;

__device__ __forceinline__ uint bf16h(float f) {           // f32 -> bf16 bits (RNE)
    uint u = __float_as_uint(f);
    return (u + 0x7fffu + ((u >> 16) & 1u)) >> 16;
}
__device__ __forceinline__ float bf16f(uint h) { return __uint_as_float(h << 16); }

__device__ __forceinline__ void bce_terms(float val, float lab, float p, float ng,
                                          float* A, float* B, float* pOK, float* nOK,
                                          float* tp, float* tn) {
    float tot = p + ng;
    float target = p / fmaxf(tot, 1e-8f);
    float ls  = (val >= 0.f) ? -log1pf(expf(-val)) : (val  - log1pf(expf( val)));
    float lns = (val <= 0.f) ? -log1pf(expf( val)) : (-val - log1pf(expf(-val)));
    *A = lab*tot*target*ls;
    *B = lab*tot*(1.f - target)*lns;
    *pOK = (val >= 0.f) ? lab*p : 0.f;
    *nOK = (val <  0.f) ? lab*ng : 0.f;
    *tp = p*lab; *tn = ng*lab;
}

// ---------------- prep bodies ----------------
// tight counting sort (no padding) + exact prefix sums
__device__ void sort_body(int l, int t, const int* __restrict__ rule,
                          int* __restrict__ sorted, int* __restrict__ prefix) {
    __shared__ int hist[R_], cursor[R_], pre[R_+1];
    if (t < R_) hist[t] = 0;
    __syncthreads();
    for (int m = t; m < MM; m += 256) atomicAdd(&hist[rule[l*MM + m]], 1);
    __syncthreads();
    if (t == 0) {
        pre[0] = 0;
        for (int r = 0; r < R_; r++) { pre[r+1] = pre[r] + hist[r]; cursor[r] = pre[r]; }
    }
    __syncthreads();
    if (t < R_+1) prefix[l*(R_+1) + t] = pre[t];
    for (int m = t; m < MM; m += 256) {
        int r = rule[l*MM + m];
        int p = atomicAdd(&cursor[r], 1);
        sorted[l*MM + p] = m;
    }
}

// embed + fused eval for init nodes (one wave = one node; block = 4 nodes)
__device__ void embed_body(int b, int t, const float* __restrict__ itab,
                           const float* __restrict__ stab,
                           const int* __restrict__ thax, const int* __restrict__ sine,
                           float* __restrict__ store,
                           const float* __restrict__ w_eval, const float* __restrict__ b_eval,
                           const float* __restrict__ t_eval, const float* __restrict__ pt,
                           const float* __restrict__ pos, const float* __restrict__ neg,
                           const int* __restrict__ labeled, float* __restrict__ partials) {
    __shared__ float ered[4][6];
    int gid = b*256 + t;
    int n = gid >> 6, d = (gid & 63) << 2;
    int th = thax[n], si = sine[n];
    const float4 a = *(const float4*)&itab[th*D_ + d];
    const float4 bb = *(const float4*)&stab[si*D_ + d];
    float4 o; o.x = a.x+bb.x; o.y = a.y+bb.y; o.z = a.z+bb.z; o.w = a.w+bb.w;
    *(float4*)&store[(size_t)n*D_ + d] = o;
    const float4 we = *(const float4*)&w_eval[d];
    float pv = o.x*we.x + o.y*we.y + o.z*we.z + o.w*we.w;
    #pragma unroll
    for (int off = 32; off > 0; off >>= 1) pv += __shfl_xor(pv, off);
    int wvid = t >> 6;
    if ((t & 63) == 0) {
        float val = pv + b_eval[0] + pt[0]*t_eval[0];
        float A, B, pOK, nOK, tp, tn;
        bce_terms(val, (float)labeled[n], pos[n], neg[n], &A, &B, &pOK, &nOK, &tp, &tn);
        ered[wvid][0]=A; ered[wvid][1]=B; ered[wvid][2]=pOK;
        ered[wvid][3]=nOK; ered[wvid][4]=tp; ered[wvid][5]=tn;
    }
    __syncthreads();
    if (t < 6) partials[((size_t)LL*NTILE + b)*6 + t] =
        ered[0][t] + ered[1][t] + ered[2][t] + ered[3][t];
}

// Ph[((r*KSn + ks)*NT + nt)*64 + lane][j] = bf16(W[r][ks*32 + (lane>>4)*8 + j][nt*16 + (lane&15)])
__device__ void pack_body(int gid, const float* __restrict__ W,
                          ushort* __restrict__ Ph, int KSn) {
    int lane = gid & 63;
    int nt   = (gid >> 6) & 15;
    int ks   = (gid >> 10) % KSn;
    int r    = gid / (1024*KSn);
    int K = KSn*32;
    int k0 = ks*32 + (lane >> 4)*8;
    int c  = nt*16 + (lane & 15);
    const float* src = W + ((size_t)r*K + k0)*256 + c;
    uint h[8];
    #pragma unroll
    for (int j = 0; j < 8; j++) h[j] = bf16h(src[(size_t)j*256]);
    size_t o = (size_t)gid*8;
    *(uint4*)&Ph[o] = make_uint4(h[0]|(h[1]<<16), h[2]|(h[3]<<16), h[4]|(h[5]<<16), h[6]|(h[7]<<16));
}

__global__ __launch_bounds__(256) void prep_kernel(
        const int* __restrict__ drule, int* __restrict__ sorted, int* __restrict__ prefix,
        const float* __restrict__ itab, const float* __restrict__ stab,
        const int* __restrict__ thax, const int* __restrict__ sine,
        float* __restrict__ store,
        const float* __restrict__ W1, ushort* __restrict__ P1h,
        const float* __restrict__ W2, ushort* __restrict__ P2h,
        const float* __restrict__ w_eval, const float* __restrict__ b_eval,
        const float* __restrict__ t_eval, const float* __restrict__ pt,
        const float* __restrict__ pos, const float* __restrict__ neg,
        const int* __restrict__ labeled, float* __restrict__ partials) {
    int b = blockIdx.x, t = threadIdx.x;
    if (b < LL) {
        sort_body(b, t, drule, sorted, prefix);
    } else if (b < LL + EMB_BLKS) {
        embed_body(b - LL, t, itab, stab, thax, sine, store,
                   w_eval, b_eval, t_eval, pt, pos, neg, labeled, partials);
    } else if (b < LL + EMB_BLKS + PK1_BLKS) {
        pack_body((b - LL - EMB_BLKS)*256 + t, W1, P1h, KS1);
    } else {
        pack_body((b - LL - EMB_BLKS - PK1_BLKS)*256 + t, W2, P2h, KS2);
    }
}

// ---------------- one DAG layer + fused eval ----------------
// 256 tight-packed 16-node tiles (1 block/CU); 16 waves, 1 n-tile per wave.
// Straddle tiles (rule boundary inside tile, <=7/layer) run one GEMM pass per rule.
// Padded-row LDS layout (no XOR swizzle): <=2-way bank aliasing on all accesses.
__global__ __launch_bounds__(1024) void layer_kernel(float* __restrict__ store,
        const int* __restrict__ sorted, const int* __restrict__ prefix,
        const int* __restrict__ parents,
        const ushort* __restrict__ P1h, const ushort* __restrict__ P2h,
        const float* __restrict__ b1, const float* __restrict__ t1,
        const float* __restrict__ b2, const float* __restrict__ pt,
        const float* __restrict__ w_eval, const float* __restrict__ b_eval,
        const float* __restrict__ t_eval,
        const float* __restrict__ pos, const float* __restrict__ neg,
        const int* __restrict__ labeled, float* __restrict__ partials, int l) {
    __shared__ ushort Xh[16*XROW], Xl[16*XROW];   // 16 rows x 512 bf16 hi/lo (padded rows)
    __shared__ ushort Hh[16*HROW], Hl[16*HROW];
    __shared__ int idx_s[16];
    __shared__ int pre_s[R_+1];
    __shared__ float vred[16][17];
    const int t = threadIdx.x, lane = t & 63, wv = t >> 6;   // wv = 0..15
    const int crow = lane & 15, kg = lane >> 4;
    const int tl = blockIdx.x;
    const int col = wv*16 + crow;
    const float tw = pt[1];
    const float bev = b_eval[0] + pt[0]*t_eval[0];
    const float we  = w_eval[col];

    if (t < R_+1) pre_s[t] = prefix[l*(R_+1) + t];
    // ---- gather: wave wv stages row wv (2 parent halves, float4/lane) ----
    const int m = sorted[l*MM + tl*16 + wv];
    if (lane == 0) idx_s[wv] = m;
    #pragma unroll
    for (int half = 0; half < 2; half++) {
        int pn = parents[(l*MM + m)*2 + half];
        float4 v = *(const float4*)&store[(size_t)pn*D_ + lane*4];
        uint h0 = bf16h(v.x), h1 = bf16h(v.y), h2 = bf16h(v.z), h3 = bf16h(v.w);
        uint l0 = bf16h(v.x - bf16f(h0)), l1 = bf16h(v.y - bf16f(h1));
        uint l2 = bf16h(v.z - bf16f(h2)), l3 = bf16h(v.w - bf16f(h3));
        int e = wv*XROW + half*256 + lane*4;
        *(uint2*)&Xh[e] = make_uint2(h0|(h1<<16), h2|(h3<<16));
        *(uint2*)&Xl[e] = make_uint2(l0|(l1<<16), l2|(l3<<16));
    }
    __syncthreads();

    const int row0 = tl*16;
    const int ob = NINIT + l*MM;
    // ---- rule passes: uniform tiles run once; straddle tiles once per rule ----
    for (int r = 0; r < R_; r++) {
        int lo = (row0 > pre_s[r] ? row0 : pre_s[r]) - row0;
        int hi = (row0+16 < pre_s[r+1] ? row0+16 : pre_s[r+1]) - row0;
        if (lo >= hi) continue;
        float bb1 = b1[r*H_ + col] + tw * t1[r*H_ + col];
        float bb2 = b2[r*D_ + col];

        // GEMM1: [16x512] @ W1h[512x256], 2-pass (xl, xh)
        f32x4 acc = (f32x4){bb1, bb1, bb1, bb1};
        const short8* B1hp = (const short8*)P1h + ((size_t)r*KS1*NT + wv)*64 + lane;
        #pragma unroll
        for (int ks = 0; ks < KS1; ks++) {
            int ab = crow*XROW + ks*32 + kg*8;
            short8 xh = *(const short8*)&Xh[ab];
            short8 xl = *(const short8*)&Xl[ab];
            short8 bh = B1hp[(size_t)ks*NT*64];
            acc = __builtin_amdgcn_mfma_f32_16x16x32_bf16(xl, bh, acc, 0, 0, 0);
            acc = __builtin_amdgcn_mfma_f32_16x16x32_bf16(xh, bh, acc, 0, 0, 0);
        }
        __syncthreads();                      // previous pass done reading H
        #pragma unroll
        for (int reg = 0; reg < 4; reg++) {
            int row = kg*4 + reg;
            float h = fmaxf(acc[reg], 0.f);
            uint hh = bf16h(h);
            uint hl = bf16h(h - bf16f(hh));
            Hh[row*HROW + col] = (ushort)hh;
            Hl[row*HROW + col] = (ushort)hl;
        }
        __syncthreads();

        // GEMM2: [16x256] @ W2h[256x256], 2-pass (hl, hh)
        f32x4 acc2 = (f32x4){bb2, bb2, bb2, bb2};
        const short8* B2hp = (const short8*)P2h + ((size_t)r*KS2*NT + wv)*64 + lane;
        #pragma unroll
        for (int ks = 0; ks < KS2; ks++) {
            int ab = crow*HROW + ks*32 + kg*8;
            short8 hh = *(const short8*)&Hh[ab];
            short8 hl = *(const short8*)&Hl[ab];
            short8 bh = B2hp[(size_t)ks*NT*64];
            acc2 = __builtin_amdgcn_mfma_f32_16x16x32_bf16(hl, bh, acc2, 0, 0, 0);
            acc2 = __builtin_amdgcn_mfma_f32_16x16x32_bf16(hh, bh, acc2, 0, 0, 0);
        }
        // store y + eval partial-dot for rows owned by rule r
        float pv[4];
        #pragma unroll
        for (int reg = 0; reg < 4; reg++) {
            int row = kg*4 + reg;
            if (row >= lo && row < hi)
                store[(size_t)(ob + idx_s[row])*D_ + col] = acc2[reg];
            pv[reg] = acc2[reg] * we;
        }
        #pragma unroll
        for (int off = 1; off < 16; off <<= 1) {
            #pragma unroll
            for (int reg = 0; reg < 4; reg++) pv[reg] += __shfl_xor(pv[reg], off);
        }
        if (crow == 0) {
            #pragma unroll
            for (int reg = 0; reg < 4; reg++) {
                int row = kg*4 + reg;
                if (row >= lo && row < hi) vred[row][wv] = pv[reg];
            }
        }
    }
    __syncthreads();
    // ---- fused eval tail: one row per lane (t < 16) ----
    if (t < 16) {
        float val = 0.f;
        #pragma unroll
        for (int w16 = 0; w16 < 16; w16++) val += vred[t][w16];
        int n = ob + idx_s[t];
        float A, B, pOK, nOK, tp, tn;
        bce_terms(val + bev, (float)labeled[n], pos[n], neg[n],
                  &A, &B, &pOK, &nOK, &tp, &tn);
        #pragma unroll
        for (int off = 1; off < 16; off <<= 1) {
            A   += __shfl_xor(A, off);   B  += __shfl_xor(B, off);
            pOK += __shfl_xor(pOK, off); nOK += __shfl_xor(nOK, off);
            tp  += __shfl_xor(tp, off);  tn += __shfl_xor(tn, off);
        }
        if (t == 0) {
            float* ps = &partials[((size_t)l*NTILE + tl)*6];
            ps[0]=A; ps[1]=B; ps[2]=pOK; ps[3]=nOK; ps[4]=tp; ps[5]=tn;
        }
    }
}

// ---------------- final reduce + pw + loss ----------------
__global__ __launch_bounds__(256) void final_kernel(const float* __restrict__ partials,
                                                    float* __restrict__ out) {
    int t = threadIdx.x;
    float s[6] = {0.f, 0.f, 0.f, 0.f, 0.f, 0.f};
    for (int g = t; g < NPART; g += 256) {
        #pragma unroll
        for (int j = 0; j < 6; j++) s[j] += partials[g*6 + j];
    }
    __shared__ float red[256];
    #pragma unroll
    for (int j = 0; j < 6; j++) {
        __syncthreads();
        red[t] = s[j];
        __syncthreads();
        for (int st = 128; st > 0; st >>= 1) {
            if (t < st) red[t] += red[t + st];
            __syncthreads();
        }
        s[j] = red[0];
    }
    if (t == 0) {
        float pw = s[5] / fmaxf(s[4], 1e-8f);
        out[0] = -(pw*s[0] + s[1]);
        out[1] = s[2]; out[2] = s[3]; out[3] = s[4]; out[4] = s[5];
    }
}

extern "C" void kernel_launch(void* const* d_in, const int* in_sizes, int n_in,
                              void* d_out, int out_size, void* d_ws, size_t ws_size,
                              hipStream_t stream) {
    const float* pt        = (const float*)d_in[0];
    const float* init_tab  = (const float*)d_in[1];
    const float* sine_tab  = (const float*)d_in[2];
    const float* W1        = (const float*)d_in[3];
    const float* b1        = (const float*)d_in[4];
    const float* t1        = (const float*)d_in[5];
    const float* W2        = (const float*)d_in[6];
    const float* b2        = (const float*)d_in[7];
    const float* w_eval    = (const float*)d_in[8];
    const float* b_eval    = (const float*)d_in[9];
    const float* t_eval    = (const float*)d_in[10];
    const float* pos       = (const float*)d_in[11];
    const float* neg       = (const float*)d_in[12];
    const int*   init_thax = (const int*)d_in[13];
    const int*   init_sine = (const int*)d_in[14];
    const int*   drule     = (const int*)d_in[15];
    const int*   dparents  = (const int*)d_in[16];
    const int*   labeled   = (const int*)d_in[17];
    float* out = (float*)d_out;

    // workspace layout (bytes, all 16-aligned)
    char* w = (char*)d_ws;
    const size_t STORE_B = (size_t)NTOT * D_ * 4;            // 75,497,472
    const size_t SORT_B  = (size_t)LL * MM * 4;              //    262,144
    const size_t PREF_B  = 1024;                             // LL*9*4 padded
    const size_t P1_B    = (size_t)R_*KS1*NT*64*8*2;         //  2,097,152
    const size_t P2_B    = (size_t)R_*KS2*NT*64*8*2;         //  1,048,576
    float*  store    = (float*) w;                    w += STORE_B;
    int*    sorted   = (int*)   w;                    w += SORT_B;
    int*    prefix   = (int*)   w;                    w += PREF_B;
    ushort* P1h      = (ushort*)w;                    w += P1_B;
    ushort* P2h      = (ushort*)w;                    w += P2_B;
    float*  partials = (float*) w;                    // NPART*6*4 = 147,456

    prep_kernel<<<PREP_BLKS, 256, 0, stream>>>(drule, sorted, prefix,
                                               init_tab, sine_tab,
                                               init_thax, init_sine, store,
                                               W1, P1h, W2, P2h,
                                               w_eval, b_eval, t_eval, pt,
                                               pos, neg, labeled, partials);
    for (int l = 0; l < LL; l++)
        layer_kernel<<<NTILE, 1024, 0, stream>>>(store, sorted, prefix, dparents,
                                                 P1h, P2h, b1, t1, b2, pt,
                                                 w_eval, b_eval, t_eval,
                                                 pos, neg, labeled, partials, l);
    final_kernel<<<1, 256, 0, stream>>>(partials, out);
}